// Round 3
// baseline (712.231 us; speedup 1.0000x reference)
//
#include <hip/hip_runtime.h>
#include <math.h>

// SSVI: out = y*0.5*(1 + rho*pl + sqrt(pl^2 + 2 rho pl + 1)), pl = phi*logm,
// phi = eta / (y^gamma * (1+y)^(1-gamma)).
// Outputs (concat flat): [out, zeros, d out/d logm, d2 out/d logm^2], each N floats.
//
// Closed-form derivatives:
//   s   = sqrt(pl^2 + 2 rho pl + 1)
//   g1  = 0.5*y*phi*(rho + (pl+rho)/s)
//   g2  = 0.5*y*phi^2*(1 - rho^2)/s^3     [since s^2-(pl+rho)^2 = 1-rho^2]
//
// R1: libm powf (2x/elem) -> hw log2/exp2/rsq: kernel 344 -> ~205 us.
// R2 (this): memory-side tuning toward the ~110-130 us mixed-stream floor:
//   - PLAIN loads (no nt): inputs (256 MiB) are Infinity-Cache-resident across
//     iterations (round-0 FETCH_SIZE=134MB = 50% L3-served); the nt hint tells
//     the cache not to retain -> wrong for re-read inputs. NT kept on stores
//     only (streaming, never re-read).
//   - 16 elements/thread (4 x f32x4 chunks), ALL input loads issued before any
//     compute -> 8 loads in flight/thread for MLP.
//   - Exact-grid unguarded fast path (N=2^25 divides block tile 1024 f32x4).

typedef float f32x4 __attribute__((ext_vector_type(4)));

__device__ __forceinline__ float ex2(float x) { return __builtin_amdgcn_exp2f(x); }
__device__ __forceinline__ float lg2(float x) { return __builtin_amdgcn_logf(x); }
__device__ __forceinline__ float rsq(float x) { return __builtin_amdgcn_rsqf(x); }

#define LOG2E 1.4426950408889634f
#define CHUNKS 4
#define BLOCK 256
#define TILE (BLOCK * CHUNKS)   // f32x4 per block

template <bool GUARD>
__global__ __launch_bounds__(BLOCK) void ssvi_kernel(
    const f32x4* __restrict__ logm4,
    const f32x4* __restrict__ y4,
    const float* __restrict__ raw_rho,
    const float* __restrict__ raw_eta,
    const float* __restrict__ raw_gamma,
    f32x4* __restrict__ out4,   // 4*n4 f32x4s
    int n4, int base0)
{
    // Uniform params via hw transcendentals (amortized over 16 elements).
    const float rr    = raw_rho[0];
    const float e2t   = ex2(2.0f * LOG2E * rr);
    const float rho   = (e2t - 1.0f) * __builtin_amdgcn_rcpf(e2t + 1.0f);
    const float eta   = ex2(LOG2E * raw_eta[0]);
    const float gamma = ex2(LOG2E * raw_gamma[0]);
    const float omr2  = 1.0f - rho * rho;
    const float two_rho = rho + rho;

    const size_t base = (size_t)base0 + (size_t)blockIdx.x * TILE + threadIdx.x;
    const f32x4 zero4 = {0.0f, 0.0f, 0.0f, 0.0f};
    const size_t sn4 = (size_t)n4;

    // Issue all loads first: 8 global_load_dwordx4 in flight per thread.
    f32x4 lm[CHUNKS], yv[CHUNKS];
    #pragma unroll
    for (int c = 0; c < CHUNKS; ++c) {
        const size_t idx = base + (size_t)c * BLOCK;
        if (GUARD && idx >= sn4) continue;
        lm[c] = logm4[idx];
        yv[c] = y4[idx];
    }

    #pragma unroll
    for (int c = 0; c < CHUNKS; ++c) {
        const size_t idx = base + (size_t)c * BLOCK;
        if (GUARD && idx >= sn4) continue;

        f32x4 o, g1, g2;
        #pragma unroll
        for (int k = 0; k < 4; ++k) {
            float y = yv[c][k];
            float l = lm[c][k];

            // phi = eta * exp2(-(l2y1 + gamma*(l2y - l2y1)))
            float l2y  = lg2(y);
            float l2y1 = lg2(1.0f + y);
            float t    = fmaf(gamma, l2y - l2y1, l2y1);
            float phi  = eta * ex2(-t);

            float pl  = phi * l;
            float s2  = fmaf(pl, pl, fmaf(two_rho, pl, 1.0f));
            float is  = rsq(s2);           // 1/s
            float s   = s2 * is;           // sqrt(s2)
            float hy  = 0.5f * y;
            float hphi = hy * phi;
            float is3 = (is * is) * is;

            o[k]  = hy * (fmaf(rho, pl, 1.0f) + s);
            g1[k] = hphi * fmaf(pl + rho, is, rho);
            g2[k] = (hphi * phi) * (omr2 * is3);
        }

        __builtin_nontemporal_store(o,     &out4[idx]);
        __builtin_nontemporal_store(zero4, &out4[sn4 + idx]);        // grad_ttm1
        __builtin_nontemporal_store(g1,    &out4[2 * sn4 + idx]);
        __builtin_nontemporal_store(g2,    &out4[3 * sn4 + idx]);
    }
}

extern "C" void kernel_launch(void* const* d_in, const int* in_sizes, int n_in,
                              void* d_out, int out_size, void* d_ws, size_t ws_size,
                              hipStream_t stream) {
    const f32x4* logm4 = (const f32x4*)d_in[0];
    const f32x4* y4    = (const f32x4*)d_in[1];
    const float* raw_rho   = (const float*)d_in[2];
    const float* raw_eta   = (const float*)d_in[3];
    const float* raw_gamma = (const float*)d_in[4];
    f32x4* out4 = (f32x4*)d_out;

    int n  = in_sizes[0];        // 33554432 = 2^25, divisible by 4*TILE
    int n4 = n / 4;
    int nfull = (n4 / TILE) * TILE;
    int rem   = n4 - nfull;

    if (nfull > 0) {
        ssvi_kernel<false><<<nfull / TILE, BLOCK, 0, stream>>>(
            logm4, y4, raw_rho, raw_eta, raw_gamma, out4, n4, 0);
    }
    if (rem > 0) {   // never taken for N=2^25; kept for safety
        ssvi_kernel<true><<<(rem + TILE - 1) / TILE, BLOCK, 0, stream>>>(
            logm4, y4, raw_rho, raw_eta, raw_gamma, out4, n4, nfull);
    }
}